// Round 1
// baseline (188.410 us; speedup 1.0000x reference)
//
#include <hip/hip_runtime.h>
#include <math.h>

namespace {

constexpr int Dm = 2048;

// x[b][i] = feats[b][i] + mod_emb[b/8][i],  b = m*8+s, 64 rows
__global__ void k_x(const float* __restrict__ feats, const float* __restrict__ mod,
                    float* __restrict__ xbuf) {
  int idx = blockIdx.x * 256 + threadIdx.x;   // 131072 total
  int b = idx >> 11, i = idx & 2047;
  xbuf[idx] = feats[idx] + mod[((b >> 3) << 11) + i];
}

// summ[m][i] = mean_s feats[m][s][i] + mod_emb[m][i]
__global__ void k_summ(const float* __restrict__ feats, const float* __restrict__ mod,
                       float* __restrict__ summ) {
  int idx = blockIdx.x * 256 + threadIdx.x;   // 16384 total
  int m = idx >> 11, i = idx & 2047;
  float s = 0.f;
#pragma unroll
  for (int t = 0; t < 8; ++t) s += feats[((m * 8 + t) << 11) + i];
  summ[idx] = s * 0.125f + mod[idx];
}

// out[j] = act( dot(Arow(j), W[j*ldw+cofs .. +IN]) + b1[j] + b2[j] )
// Arow(j) = A + (j/G)*IN. ACT: 0 none, 1 relu, 2 gelu(exact)
template <int ACT>
__global__ void k_matvec(const float* __restrict__ A, int IN, int G,
                         const float* __restrict__ W, int ldw, int cofs,
                         const float* __restrict__ b1, const float* __restrict__ b2,
                         float* __restrict__ out, int OUT) {
  __shared__ float As[4096];
  int j0 = blockIdx.x * 4;
  const float* Arow = A + (size_t)(j0 / G) * IN;
  for (int t = threadIdx.x; t < IN; t += 256) As[t] = Arow[t];
  __syncthreads();
  int wave = threadIdx.x >> 6, lane = threadIdx.x & 63;
  int j = j0 + wave;
  if (j >= OUT) return;
  const float* Wr = W + (size_t)j * ldw + cofs;
  float acc = 0.f;
  for (int i = lane * 4; i < IN; i += 256) {
    float4 w = *(const float4*)(Wr + i);
    float4 a = *(const float4*)(As + i);
    acc += w.x * a.x + w.y * a.y + w.z * a.z + w.w * a.w;
  }
#pragma unroll
  for (int o = 32; o > 0; o >>= 1) acc += __shfl_down(acc, o, 64);
  if (lane == 0) {
    float v = acc;
    if (b1) v += b1[j];
    if (b2) v += b2[j];
    if (ACT == 1) v = fmaxf(v, 0.f);
    if (ACT == 2) v = 0.5f * v * (1.f + erff(v * 0.70710678118654752f));
    out[j] = v;
  }
}

// C[m][j] = act( dot(A[m*lda ..+2048], W[j*ldw ..]) + b1[j] + b2[j] ), m<8
template <int ACT>
__global__ void k_gemm8(const float* __restrict__ A, int lda,
                        const float* __restrict__ W, int ldw,
                        const float* __restrict__ b1, const float* __restrict__ b2,
                        float* __restrict__ out, int ldo, int OUT) {
  __shared__ float As[8 * Dm];   // 64 KB
  for (int t = threadIdx.x; t < 8 * Dm; t += 256) {
    int m = t >> 11, i = t & 2047;
    As[t] = A[(size_t)m * lda + i];
  }
  __syncthreads();
  int wave = threadIdx.x >> 6, lane = threadIdx.x & 63;
  int j = blockIdx.x * 4 + wave;
  if (j >= OUT) return;
  const float* Wr = W + (size_t)j * ldw;
  float acc[8] = {0.f, 0.f, 0.f, 0.f, 0.f, 0.f, 0.f, 0.f};
  for (int i = lane * 4; i < Dm; i += 256) {
    float4 w = *(const float4*)(Wr + i);
#pragma unroll
    for (int m = 0; m < 8; ++m) {
      float4 a = *(const float4*)(As + (m << 11) + i);
      acc[m] += w.x * a.x + w.y * a.y + w.z * a.z + w.w * a.w;
    }
  }
#pragma unroll
  for (int m = 0; m < 8; ++m) {
    float v = acc[m];
#pragma unroll
    for (int o = 32; o > 0; o >>= 1) v += __shfl_down(v, o, 64);
    acc[m] = v;
  }
  if (lane == 0) {
    float bb = 0.f;
    if (b1) bb += b1[j];
    if (b2) bb += b2[j];
#pragma unroll
    for (int m = 0; m < 8; ++m) {
      float v = acc[m] + bb;
      if (ACT == 1) v = fmaxf(v, 0.f);
      out[(size_t)m * ldo + j] = v;
    }
  }
}

// routing head: rw (normalized), quantile(0.9) threshold, mask row 0
__global__ void k_route3(const float* __restrict__ h2, const float* __restrict__ rW3,
                         const float* __restrict__ rb3, float* __restrict__ rwv,
                         float* __restrict__ maskv, float* __restrict__ out_rw) {
  __shared__ float sig[8];
  __shared__ float wm[64];
  __shared__ float sv[64];
  int wave = threadIdx.x >> 6, lane = threadIdx.x & 63;   // 256 threads
  for (int mi = 0; mi < 2; ++mi) {
    int m = wave + mi * 4;
    float acc = 0.f;
    for (int i = lane * 4; i < 1024; i += 256) {
      float4 w = *(const float4*)(rW3 + i);
      float4 a = *(const float4*)(h2 + m * 1024 + i);
      acc += w.x * a.x + w.y * a.y + w.z * a.z + w.w * a.w;
    }
#pragma unroll
    for (int o = 32; o > 0; o >>= 1) acc += __shfl_down(acc, o, 64);
    if (lane == 0) {
      float z = acc + rb3[0];
      sig[m] = 1.f / (1.f + expf(-z));
    }
  }
  __syncthreads();
  if (threadIdx.x < 64) {
    float tot = 0.f;
#pragma unroll
    for (int m = 0; m < 8; ++m) tot += sig[m];
    int r = threadIdx.x >> 3, c = threadIdx.x & 7;
    wm[threadIdx.x] = (sig[r] / tot) * (sig[c] / tot);
    if (threadIdx.x < 8) {
      float v = sig[threadIdx.x] / tot;
      rwv[threadIdx.x] = v;
      out_rw[threadIdx.x] = v;
    }
  }
  __syncthreads();
  if (threadIdx.x < 64) {
    float v = wm[threadIdx.x];
    int rank = 0;
    for (int t = 0; t < 64; ++t) {
      float u = wm[t];
      rank += (u < v) || (u == v && t < (int)threadIdx.x);
    }
    sv[rank] = v;   // ascending
  }
  __syncthreads();
  if (threadIdx.x < 8) {
    double pos = 0.9 * 63.0;        // matches np.quantile 'linear'
    int lo = (int)pos;
    double frac = pos - (double)lo;
    float thr = (float)((double)sv[lo] + frac * ((double)sv[lo + 1] - (double)sv[lo]));
    float v = wm[threadIdx.x];      // row 0 of wmat
    maskv[threadIdx.x] = (v < thr) ? -1e9f : 0.f;
  }
}

// qw[m][h][i] = sum_d' q0[m][h*128+d'] * W_in[(2048+h*128+d')][i]
__global__ void k_qw(const float* __restrict__ q0, const float* __restrict__ W_in,
                     float* __restrict__ qw) {
  __shared__ float qs[8 * 128];
  int h = blockIdx.y;
  int i = blockIdx.x * 128 + threadIdx.x;   // 128 threads
  for (int t = threadIdx.x; t < 8 * 128; t += 128) {
    int m = t >> 7, d = t & 127;
    qs[t] = q0[m * Dm + h * 128 + d];
  }
  __syncthreads();
  float acc[8] = {0.f, 0.f, 0.f, 0.f, 0.f, 0.f, 0.f, 0.f};
  const float* Wb = W_in + (size_t)(Dm + h * 128) * Dm + i;
  for (int d = 0; d < 128; ++d) {
    float w = Wb[(size_t)d * Dm];
#pragma unroll
    for (int m = 0; m < 8; ++m) acc[m] += w * qs[m * 128 + d];
  }
#pragma unroll
  for (int m = 0; m < 8; ++m) qw[(size_t)(m * 16 + h) * Dm + i] = acc[m];
}

// attw[m][h][k] = softmax_k( dot(qw[m,h,:], x[m,k,:]) / sqrt(128) + mask0[k] )
__global__ void k_attnw(const float* __restrict__ qw, const float* __restrict__ xbuf,
                        const float* __restrict__ maskv, float* __restrict__ attw) {
  int mh = blockIdx.x;
  int m = mh >> 4;
  int lane = threadIdx.x;   // 64 threads
  const float* qr = qw + (size_t)mh * Dm;
  float sc[8];
#pragma unroll
  for (int k = 0; k < 8; ++k) {
    const float* xr = xbuf + (size_t)(m * 8 + k) * Dm;
    float acc = 0.f;
    for (int i = lane * 4; i < Dm; i += 256) {
      float4 a = *(const float4*)(qr + i);
      float4 b = *(const float4*)(xr + i);
      acc += a.x * b.x + a.y * b.y + a.z * b.z + a.w * b.w;
    }
#pragma unroll
    for (int o = 32; o > 0; o >>= 1) acc += __shfl_xor(acc, o, 64);
    sc[k] = acc * 0.08838834764831845f + maskv[k];
  }
  float mx = sc[0];
#pragma unroll
  for (int k = 1; k < 8; ++k) mx = fmaxf(mx, sc[k]);
  float se = 0.f;
#pragma unroll
  for (int k = 0; k < 8; ++k) { sc[k] = expf(sc[k] - mx); se += sc[k]; }
  float inv = 1.f / se;
  if (lane < 8) attw[mh * 8 + lane] = sc[lane] * inv;
}

// xbar[h][i] = (1/8) sum_m sum_k attw[m,h,k] * x[m*8+k][i]
__global__ void k_xbar(const float* __restrict__ attw, const float* __restrict__ xbuf,
                       float* __restrict__ xbar) {
  __shared__ float aw[64];
  int h = blockIdx.y;
  int i = blockIdx.x * 256 + threadIdx.x;
  if (threadIdx.x < 64) {
    int m = threadIdx.x >> 3, k = threadIdx.x & 7;
    aw[threadIdx.x] = attw[(m * 16 + h) * 8 + k];
  }
  __syncthreads();
  float acc = 0.f;
#pragma unroll
  for (int b = 0; b < 64; ++b) acc += aw[b] * xbuf[(size_t)b * Dm + i];
  xbar[(size_t)h * Dm + i] = acc * 0.125f;
}

// gate: logits -> softmax -> top3(stable) -> gates = softmax(top vals)
__global__ void k_gate(const float* __restrict__ g, const float* __restrict__ gW2,
                       const float* __restrict__ gb2, float* __restrict__ gates,
                       int* __restrict__ topi) {
  __shared__ float logits[8];
  int wave = threadIdx.x >> 6, lane = threadIdx.x & 63;   // 512 threads
  float acc = 0.f;
  for (int i = lane * 4; i < 1024; i += 256) {
    float4 w = *(const float4*)(gW2 + wave * 1024 + i);
    float4 a = *(const float4*)(g + i);
    acc += w.x * a.x + w.y * a.y + w.z * a.z + w.w * a.w;
  }
#pragma unroll
  for (int o = 32; o > 0; o >>= 1) acc += __shfl_down(acc, o, 64);
  if (lane == 0) logits[wave] = acc + gb2[wave];
  __syncthreads();
  if (threadIdx.x == 0) {
    float mx = logits[0];
    for (int e = 1; e < 8; ++e) mx = fmaxf(mx, logits[e]);
    float p[8], se = 0.f;
    for (int e = 0; e < 8; ++e) { p[e] = expf(logits[e] - mx); se += p[e]; }
    for (int e = 0; e < 8; ++e) p[e] /= se;
    int used[8] = {0, 0, 0, 0, 0, 0, 0, 0};
    float tv[3]; int ti[3];
    for (int kk = 0; kk < 3; ++kk) {
      float bv = -1.f; int bi = -1;
      for (int e = 0; e < 8; ++e)
        if (!used[e] && p[e] > bv) { bv = p[e]; bi = e; }
      used[bi] = 1; tv[kk] = bv; ti[kk] = bi;
    }
    float m2 = tv[0];   // descending
    float s2 = 0.f, gg[3];
    for (int kk = 0; kk < 3; ++kk) { gg[kk] = expf(tv[kk] - m2); s2 += gg[kk]; }
    for (int kk = 0; kk < 3; ++kk) { gates[kk] = gg[kk] / s2; topi[kk] = ti[kk]; }
  }
}

// expert matvec with runtime-selected expert index
template <int ACT>
__global__ void k_expert_mv(const float* __restrict__ A, int IN, int a_stride_kk,
                            const float* __restrict__ Wbase, size_t wstride,
                            const float* __restrict__ bbase, int bstride,
                            const int* __restrict__ topi,
                            float* __restrict__ out, int OUT) {
  extern __shared__ float As[];
  int kk = blockIdx.y;
  int ei = topi[kk];
  const float* Arow = A + (size_t)kk * a_stride_kk;
  for (int t = threadIdx.x; t < IN; t += 256) As[t] = Arow[t];
  __syncthreads();
  int wave = threadIdx.x >> 6, lane = threadIdx.x & 63;
  int j = blockIdx.x * 4 + wave;
  if (j >= OUT) return;
  const float* Wr = Wbase + (size_t)ei * wstride + (size_t)j * IN;
  float acc = 0.f;
  for (int i = lane * 4; i < IN; i += 256) {
    float4 w = *(const float4*)(Wr + i);
    float4 a = *(const float4*)(As + i);
    acc += w.x * a.x + w.y * a.y + w.z * a.z + w.w * a.w;
  }
#pragma unroll
  for (int o = 32; o > 0; o >>= 1) acc += __shfl_down(acc, o, 64);
  if (lane == 0) {
    float v = acc + bbase[(size_t)ei * bstride + j];
    if (ACT == 2) v = 0.5f * v * (1.f + erff(v * 0.70710678118654752f));
    out[(size_t)kk * OUT + j] = v;
  }
}

// per-expert LayerNorm + gated combine -> fused[0:2048]
__global__ void k_final(const float* __restrict__ y, const float* __restrict__ gates,
                        const int* __restrict__ topi,
                        const float* __restrict__ e_gamma, const float* __restrict__ e_beta,
                        float* __restrict__ outp) {
  __shared__ float r1[256], r2[256];
  __shared__ float smu, srstd;
  float fused[8];
#pragma unroll
  for (int t = 0; t < 8; ++t) fused[t] = 0.f;
  for (int kk = 0; kk < 3; ++kk) {
    int ei = topi[kk];
    float gk = gates[kk];
    const float* yr = y + (size_t)kk * Dm;
    float s = 0.f, ss = 0.f;
#pragma unroll
    for (int t = 0; t < 8; ++t) {
      float v = yr[threadIdx.x + 256 * t];
      s += v; ss += v * v;
    }
    r1[threadIdx.x] = s; r2[threadIdx.x] = ss;
    __syncthreads();
    for (int o = 128; o > 0; o >>= 1) {
      if (threadIdx.x < o) {
        r1[threadIdx.x] += r1[threadIdx.x + o];
        r2[threadIdx.x] += r2[threadIdx.x + o];
      }
      __syncthreads();
    }
    if (threadIdx.x == 0) {
      float mu = r1[0] * (1.f / 2048.f);
      float var = r2[0] * (1.f / 2048.f) - mu * mu;
      smu = mu;
      srstd = rsqrtf(var + 1e-5f);
    }
    __syncthreads();
    float mu = smu, rstd = srstd;
#pragma unroll
    for (int t = 0; t < 8; ++t) {
      int d = threadIdx.x + 256 * t;
      float v = (yr[d] - mu) * rstd * e_gamma[(size_t)ei * Dm + d] + e_beta[(size_t)ei * Dm + d];
      fused[t] += gk * v;
    }
    __syncthreads();
  }
#pragma unroll
  for (int t = 0; t < 8; ++t) outp[threadIdx.x + 256 * t] = fused[t];
}

}  // namespace

extern "C" void kernel_launch(void* const* d_in, const int* in_sizes, int n_in,
                              void* d_out, int out_size, void* d_ws, size_t ws_size,
                              hipStream_t stream) {
  const float* feats   = (const float*)d_in[0];
  const float* context = (const float*)d_in[1];
  const float* mod_emb = (const float*)d_in[2];
  const float* rW1 = (const float*)d_in[3];
  const float* rb1 = (const float*)d_in[4];
  const float* rW2 = (const float*)d_in[5];
  const float* rb2 = (const float*)d_in[6];
  const float* rW3 = (const float*)d_in[7];
  const float* rb3 = (const float*)d_in[8];
  const float* W_in  = (const float*)d_in[9];
  const float* b_in  = (const float*)d_in[10];
  const float* W_out = (const float*)d_in[11];
  const float* b_out = (const float*)d_in[12];
  const float* gW1 = (const float*)d_in[13];
  const float* gb1 = (const float*)d_in[14];
  const float* gW2 = (const float*)d_in[15];
  const float* gb2 = (const float*)d_in[16];
  const float* eW1 = (const float*)d_in[17];
  const float* eb1 = (const float*)d_in[18];
  const float* eW2 = (const float*)d_in[19];
  const float* eb2 = (const float*)d_in[20];
  const float* e_gamma = (const float*)d_in[21];
  const float* e_beta  = (const float*)d_in[22];
  float* out = (float*)d_out;
  float* ws = (float*)d_ws;

  float* xbuf  = ws;                 // 131072
  float* summ  = xbuf + 131072;      // 16384
  float* cterm = summ + 16384;       // 2048
  float* h1    = cterm + 2048;       // 16384
  float* h2    = h1 + 16384;         // 8192
  float* rwv   = h2 + 8192;          // 8
  float* maskv = rwv + 8;            // 8
  float* q0    = maskv + 8;          // 16384 (offset mult of 4 -> 16B aligned)
  float* qw    = q0 + 16384;         // 262144
  float* attw  = qw + 262144;        // 1024
  float* xbar  = attw + 1024;        // 32768
  float* obar  = xbar + 32768;       // 2048
  float* attd  = obar + 2048;        // 2048
  float* gbuf  = attd + 2048;        // 1024
  float* gate_ws = gbuf + 1024;      // 16 (gates[3] floats, then int top[3])
  float* hh    = gate_ws + 16;       // 12288
  float* ybuf  = hh + 12288;         // 6144
  float* gates = gate_ws;
  int* topi = (int*)(gate_ws + 8);

  const int BIG = 1 << 30;

  hipLaunchKernelGGL(k_x, dim3(512), dim3(256), 0, stream, feats, mod_emb, xbuf);
  hipLaunchKernelGGL(k_summ, dim3(64), dim3(256), 0, stream, feats, mod_emb, summ);

  // cterm[j] = dot(context, rW1[j, 2048:4096])
  hipLaunchKernelGGL(k_matvec<0>, dim3(512), dim3(256), 0, stream,
                     context, 2048, BIG, rW1, 4096, 2048, (const float*)nullptr,
                     (const float*)nullptr, cterm, 2048);
  // h1 = relu(summ @ rW1[:, :2048].T + rb1 + cterm)
  hipLaunchKernelGGL(k_gemm8<1>, dim3(512), dim3(256), 0, stream,
                     summ, 2048, rW1, 4096, rb1, cterm, h1, 2048, 2048);
  // h2 = relu(h1 @ rW2.T + rb2)
  hipLaunchKernelGGL(k_gemm8<1>, dim3(256), dim3(256), 0, stream,
                     h1, 2048, rW2, 2048, rb2, (const float*)nullptr, h2, 1024, 1024);
  // rw, quantile threshold, mask row 0
  hipLaunchKernelGGL(k_route3, dim3(1), dim3(256), 0, stream,
                     h2, rW3, rb3, rwv, maskv, out + 2048);
  // q0[m] = x[m,0,:] @ Wq.T + bq
  hipLaunchKernelGGL(k_gemm8<0>, dim3(512), dim3(256), 0, stream,
                     xbuf, 16384, W_in, 2048, b_in, (const float*)nullptr, q0, 2048, 2048);
  // qw[m,h,:] = q0[m,hslice] @ Wk_slice
  hipLaunchKernelGGL(k_qw, dim3(16, 16), dim3(128), 0, stream, q0, W_in, qw);
  // attention weights (q=0 row only)
  hipLaunchKernelGGL(k_attnw, dim3(128), dim3(64), 0, stream, qw, xbuf, maskv, attw);
  // xbar[h] = (1/8) sum_m sum_k attw * x
  hipLaunchKernelGGL(k_xbar, dim3(8, 16), dim3(256), 0, stream, attw, xbuf, xbar);
  // obar[(h,d')] = dot(xbar[h], Wv_row) + bv
  hipLaunchKernelGGL(k_matvec<0>, dim3(512), dim3(256), 0, stream,
                     xbar, 2048, 128, W_in + (size_t)4096 * 2048, 2048, 0,
                     b_in + 4096, (const float*)nullptr, obar, 2048);
  // attended = obar @ W_out.T + b_out
  hipLaunchKernelGGL(k_matvec<0>, dim3(512), dim3(256), 0, stream,
                     obar, 2048, BIG, W_out, 2048, 0, b_out, (const float*)nullptr,
                     attd, 2048);
  // g = relu(attended @ gW1.T + gb1)
  hipLaunchKernelGGL(k_matvec<1>, dim3(256), dim3(256), 0, stream,
                     attd, 2048, BIG, gW1, 2048, 0, gb1, (const float*)nullptr,
                     gbuf, 1024);
  // gating + top3
  hipLaunchKernelGGL(k_gate, dim3(1), dim3(512), 0, stream, gbuf, gW2, gb2, gates, topi);
  // hh[kk] = gelu(attended @ eW1[ei].T + eb1[ei])
  hipLaunchKernelGGL(k_expert_mv<2>, dim3(1024, 3), dim3(256), 2048 * 4, stream,
                     attd, 2048, 0, eW1, (size_t)4096 * 2048, eb1, 4096, topi, hh, 4096);
  // y[kk] = hh[kk] @ eW2[ei].T + eb2[ei]
  hipLaunchKernelGGL(k_expert_mv<0>, dim3(512, 3), dim3(256), 4096 * 4, stream,
                     hh, 4096, 4096, eW2, (size_t)2048 * 4096, eb2, 2048, topi, ybuf, 2048);
  // LayerNorm + gated combine
  hipLaunchKernelGGL(k_final, dim3(1), dim3(256), 0, stream,
                     ybuf, gates, topi, e_gamma, e_beta, out);
}